// Round 7
// baseline (542.301 us; speedup 1.0000x reference)
//
#include <hip/hip_runtime.h>

#define CC    64
#define HH    3
#define ECC   32
#define HCdim 192
#define NEG_SLOPE 0.2f

typedef float v2f __attribute__((ext_vector_type(2)));

// ---- float <-> monotone uint key (for atomicMax on floats) ----
__device__ __forceinline__ unsigned fkey(float f) {
    int i = __float_as_int(f);
    return (i < 0) ? ~((unsigned)i) : (((unsigned)i) | 0x80000000u);
}
__device__ __forceinline__ float funkey(unsigned k) {
    int i = (k & 0x80000000u) ? (int)(k ^ 0x80000000u) : ~((int)k);
    return __int_as_float(i);
}

// K0: u[h*32+k] = sum_c We[k*192 + h*64 + c] * wt[h*192 + 64 + c]
__global__ void tm_k0(const float* __restrict__ We, const float* __restrict__ wt,
                      float* __restrict__ u) {
    int t = threadIdx.x;
    if (t >= HH * ECC) return;
    int h = t >> 5, k = t & 31;
    float s = 0.f;
    #pragma unroll
    for (int c = 0; c < CC; ++c)
        s = fmaf(We[k * HCdim + h * CC + c], wt[h * HCdim + CC + c], s);
    u[t] = s;
}

// K1: xp = x @ Wn (N x 64 @ 64 x 192), 4-row register blocking,
// fused per-node scalars sA. (NOT 8-row: that blew VGPR to 256 in R5.)
#define K1_ROWS 64
__global__ __launch_bounds__(192) void tm_k1(const float* __restrict__ x,
        const float* __restrict__ Wn, const float* __restrict__ wt,
        float* __restrict__ xp, float* __restrict__ sA, int N) {
    __shared__ float wl[CC * HCdim];     // 48 KiB [k][t]
    __shared__ float xl[K1_ROWS * CC];   // 16 KiB [r][k]
    const int t = threadIdx.x;
    const int h = t >> 6, c = t & 63;
    {
        float4* wl4 = (float4*)wl;
        const float4* Wn4 = (const float4*)Wn;
        for (int i = t; i < CC * HCdim / 4; i += 192) wl4[i] = Wn4[i];
    }
    const int base = blockIdx.x * K1_ROWS;
    const int rows = min(K1_ROWS, N - base);   // N%4==0 so rows%4==0
    {
        float4* xl4 = (float4*)xl;
        const float4* x4 = (const float4*)(x + (size_t)base * CC);
        for (int i = t; i < rows * CC / 4; i += 192) xl4[i] = x4[i];
    }
    const float w0c = wt[h * HCdim + c];
    const float w2c = wt[h * HCdim + 2 * CC + c];
    __syncthreads();
    for (int rt = 0; rt < rows; rt += 4) {
        float acc0 = 0.f, acc1 = 0.f, acc2 = 0.f, acc3 = 0.f;
        #pragma unroll 4
        for (int k = 0; k < CC; k += 4) {
            const float w0  = wl[(k + 0) * HCdim + t];
            const float w1  = wl[(k + 1) * HCdim + t];
            const float w2_ = wl[(k + 2) * HCdim + t];
            const float w3  = wl[(k + 3) * HCdim + t];
            const float4 xa = *(const float4*)&xl[(rt + 0) * CC + k];
            const float4 xb = *(const float4*)&xl[(rt + 1) * CC + k];
            const float4 xc = *(const float4*)&xl[(rt + 2) * CC + k];
            const float4 xd = *(const float4*)&xl[(rt + 3) * CC + k];
            acc0 = fmaf(xa.x, w0, fmaf(xa.y, w1, fmaf(xa.z, w2_, fmaf(xa.w, w3, acc0))));
            acc1 = fmaf(xb.x, w0, fmaf(xb.y, w1, fmaf(xb.z, w2_, fmaf(xb.w, w3, acc1))));
            acc2 = fmaf(xc.x, w0, fmaf(xc.y, w1, fmaf(xc.z, w2_, fmaf(xc.w, w3, acc2))));
            acc3 = fmaf(xd.x, w0, fmaf(xd.y, w1, fmaf(xd.z, w2_, fmaf(xd.w, w3, acc3))));
        }
        #pragma unroll
        for (int r = 0; r < 4; ++r) {
            const float v = (r == 0) ? acc0 : (r == 1) ? acc1 : (r == 2) ? acc2 : acc3;
            const int n = base + rt + r;
            xp[(size_t)n * HCdim + t] = v;
            float a0 = v * w0c, a2 = v * w2c;
            #pragma unroll
            for (int o = 32; o; o >>= 1) {
                a0 += __shfl_xor(a0, o);
                a2 += __shfl_xor(a2, o);
            }
            if (c == 0) {
                sA[n * 8 + h]     = a0;
                sA[n * 8 + 4 + h] = a2;
            }
        }
    }
}

// K_deg: degree histogram over dst
__global__ __launch_bounds__(256) void tm_deg(const int* __restrict__ ei,
        int* __restrict__ deg, int E) {
    int e = blockIdx.x * 256 + threadIdx.x;
    if (e < E) atomicAdd(&deg[ei[E + e]], 1);
}

// scanA: per-block (256) sums of deg
__global__ __launch_bounds__(256) void tm_scanA(const int* __restrict__ deg,
        int* __restrict__ bsum, int N) {
    __shared__ int sd[256];
    int t = threadIdx.x, n = blockIdx.x * 256 + t;
    sd[t] = (n < N) ? deg[n] : 0;
    __syncthreads();
    for (int o = 128; o; o >>= 1) {
        if (t < o) sd[t] += sd[t + o];
        __syncthreads();
    }
    if (!t) bsum[blockIdx.x] = sd[0];
}

// scanB: exclusive scan of block sums (nb <= 256), single block
__global__ __launch_bounds__(256) void tm_scanB(const int* __restrict__ bsum,
        int* __restrict__ boff, int nb) {
    __shared__ int sd[256];
    int t = threadIdx.x;
    int v = (t < nb) ? bsum[t] : 0;
    sd[t] = v;
    __syncthreads();
    for (int o = 1; o < 256; o <<= 1) {
        int x = (t >= o) ? sd[t - o] : 0;
        __syncthreads();
        sd[t] += x;
        __syncthreads();
    }
    if (t < nb) boff[t] = sd[t] - v;   // exclusive
}

// scanC: per-element exclusive offsets; off[N]=E; cursor=off copy
__global__ __launch_bounds__(256) void tm_scanC(const int* __restrict__ deg,
        const int* __restrict__ boff, int* __restrict__ off,
        int* __restrict__ cursor, int N) {
    __shared__ int sd[256];
    int t = threadIdx.x, n = blockIdx.x * 256 + t;
    int v = (n < N) ? deg[n] : 0;
    sd[t] = v;
    __syncthreads();
    for (int o = 1; o < 256; o <<= 1) {
        int x = (t >= o) ? sd[t - o] : 0;
        __syncthreads();
        sd[t] += x;
        __syncthreads();
    }
    if (n < N) {
        int ex = boff[blockIdx.x] + sd[t] - v;
        off[n] = ex;
        cursor[n] = ex;
        if (n == N - 1) off[N] = ex + v;
    }
}

// K_scatter2: per edge - pos = cursor[dst]++;
//   perm[pos] = {src byte-offset into xp, e byte-offset into ea};
//   alphaP[pos] = {a0,a1,a2,0} (single 16B scattered write, AoS);
//   atomicMax(segmax[dst*3+h]).
__global__ __launch_bounds__(256) void tm_scatter2(const int* __restrict__ ei,
        const float* __restrict__ ea, const float* __restrict__ u,
        const float* __restrict__ sA, int* __restrict__ cursor,
        int2* __restrict__ perm, float4* __restrict__ alphaP,
        unsigned* __restrict__ segmax, int E) {
    __shared__ float ul[HH * ECC];
    const int t = threadIdx.x;
    if (t < HH * ECC) ul[t] = u[t];
    __syncthreads();
    const int e = blockIdx.x * 256 + t;
    if (e >= E) return;
    const int src = ei[e];
    const int dst = ei[E + e];
    float av[ECC];
    const float4* p4 = (const float4*)(ea + (size_t)e * ECC);
    #pragma unroll
    for (int q = 0; q < 8; ++q) {
        float4 v = p4[q];
        av[4*q] = v.x; av[4*q+1] = v.y; av[4*q+2] = v.z; av[4*q+3] = v.w;
    }
    float d0 = 0.f, d1 = 0.f, d2 = 0.f;
    #pragma unroll
    for (int k = 0; k < ECC; ++k) {
        d0 = fmaf(av[k], ul[k], d0);
        d1 = fmaf(av[k], ul[ECC + k], d1);
        d2 = fmaf(av[k], ul[2 * ECC + k], d2);
    }
    const float4 s0 = *(const float4*)(sA + (size_t)dst * 8);
    const float4 s2 = *(const float4*)(sA + (size_t)src * 8 + 4);
    float a0 = s0.x + d0 + s2.x;
    float a1 = s0.y + d1 + s2.y;
    float a2 = s0.z + d2 + s2.z;
    a0 = (a0 >= 0.f) ? a0 : NEG_SLOPE * a0;
    a1 = (a1 >= 0.f) ? a1 : NEG_SLOPE * a1;
    a2 = (a2 >= 0.f) ? a2 : NEG_SLOPE * a2;
    const int pos = atomicAdd(&cursor[dst], 1);
    perm[pos] = make_int2(src * (HCdim * 4), e * (ECC * 4));
    alphaP[pos] = make_float4(a0, a1, a2, 0.f);
    atomicMax(&segmax[dst * 3 + 0], fkey(a0));
    atomicMax(&segmax[dst * 3 + 1], fkey(a1));
    atomicMax(&segmax[dst * 3 + 2], fkey(a2));
}

// K_agg: one block (3 waves = 3 heads) per dst node. Branch-free, pk_fma dot,
// byte-offset addressing, 4x unroll for gather-latency hiding.
__global__ __launch_bounds__(192) void tm_agg(const int2* __restrict__ perm,
        const int* __restrict__ off, const float* __restrict__ ea,
        const float* __restrict__ We, const float* __restrict__ alphaP,
        const unsigned* __restrict__ segmax, const float* __restrict__ xp,
        float* __restrict__ aggrN, int N) {
    const int n = blockIdx.x;
    const int t = threadIdx.x;
    const int h = t >> 6, lane = t & 63;
    const char* __restrict__ ea_b = (const char*)ea;
    const char* __restrict__ xp_b = (const char*)xp;
    v2f wcol2[16];
    #pragma unroll
    for (int k2 = 0; k2 < 16; ++k2) {
        wcol2[k2].x = We[(2 * k2)     * HCdim + h * CC + lane];
        wcol2[k2].y = We[(2 * k2 + 1) * HCdim + h * CC + lane];
    }
    const float m = funkey(segmax[n * 3 + h]);
    const int xoff = h * CC * 4 + lane * 4;  // byte offset within an xp row
    const int start = off[n], end = off[n + 1];
    float s = 0.f, acc = 0.f;
    int pos = start;
    for (; pos + 4 <= end; pos += 4) {
        const int4 pp0 = *(const int4*)&perm[pos];      // {so0,eo0,so1,eo1}
        const int4 pp1 = *(const int4*)&perm[pos + 2];  // {so2,eo2,so3,eo3}
        const int so0 = __builtin_amdgcn_readfirstlane(pp0.x);
        const int eo0 = __builtin_amdgcn_readfirstlane(pp0.y);
        const int so1 = __builtin_amdgcn_readfirstlane(pp0.z);
        const int eo1 = __builtin_amdgcn_readfirstlane(pp0.w);
        const int so2 = __builtin_amdgcn_readfirstlane(pp1.x);
        const int eo2 = __builtin_amdgcn_readfirstlane(pp1.y);
        const int so3 = __builtin_amdgcn_readfirstlane(pp1.z);
        const int eo3 = __builtin_amdgcn_readfirstlane(pp1.w);
        const float a0 = alphaP[(size_t)(pos + 0) * 4 + h];
        const float a1 = alphaP[(size_t)(pos + 1) * 4 + h];
        const float a2 = alphaP[(size_t)(pos + 2) * 4 + h];
        const float a3 = alphaP[(size_t)(pos + 3) * 4 + h];
        const float4* q0 = (const float4*)(ea_b + eo0);
        const float4* q1 = (const float4*)(ea_b + eo1);
        const float4* q2 = (const float4*)(ea_b + eo2);
        const float4* q3 = (const float4*)(ea_b + eo3);
        const float xj0 = *(const float*)(xp_b + so0 + xoff);
        const float xj1 = *(const float*)(xp_b + so1 + xoff);
        const float xj2 = *(const float*)(xp_b + so2 + xoff);
        const float xj3 = *(const float*)(xp_b + so3 + xoff);
        v2f d0 = {0.f, 0.f}, d1 = {0.f, 0.f}, d2 = {0.f, 0.f}, d3 = {0.f, 0.f};
        #pragma unroll
        for (int q = 0; q < 8; ++q) {
            const float4 v0 = q0[q];
            const float4 v1 = q1[q];
            const float4 v2 = q2[q];
            const float4 v3 = q3[q];
            const v2f wlo = wcol2[2 * q], whi = wcol2[2 * q + 1];
            d0 = (v2f){v0.x, v0.y} * wlo + d0;
            d0 = (v2f){v0.z, v0.w} * whi + d0;
            d1 = (v2f){v1.x, v1.y} * wlo + d1;
            d1 = (v2f){v1.z, v1.w} * whi + d1;
            d2 = (v2f){v2.x, v2.y} * wlo + d2;
            d2 = (v2f){v2.z, v2.w} * whi + d2;
            d3 = (v2f){v3.x, v3.y} * wlo + d3;
            d3 = (v2f){v3.z, v3.w} * whi + d3;
        }
        const float p0 = __expf(a0 - m);
        const float p1 = __expf(a1 - m);
        const float p2 = __expf(a2 - m);
        const float p3 = __expf(a3 - m);
        s += (p0 + p1) + (p2 + p3);
        acc = fmaf(p0 * (d0.x + d0.y), xj0, acc);
        acc = fmaf(p1 * (d1.x + d1.y), xj1, acc);
        acc = fmaf(p2 * (d2.x + d2.y), xj2, acc);
        acc = fmaf(p3 * (d3.x + d3.y), xj3, acc);
    }
    for (; pos < end; ++pos) {
        const int2 pe = perm[pos];
        const int so = __builtin_amdgcn_readfirstlane(pe.x);
        const int eo = __builtin_amdgcn_readfirstlane(pe.y);
        const float a = alphaP[(size_t)pos * 4 + h];
        const float4* q4 = (const float4*)(ea_b + eo);
        const float xj = *(const float*)(xp_b + so + xoff);
        v2f d = {0.f, 0.f};
        #pragma unroll
        for (int q = 0; q < 8; ++q) {
            const float4 v = q4[q];
            d = (v2f){v.x, v.y} * wcol2[2 * q]     + d;
            d = (v2f){v.z, v.w} * wcol2[2 * q + 1] + d;
        }
        const float p = __expf(a - m);
        s += p;
        acc = fmaf(p * (d.x + d.y), xj, acc);
    }
    aggrN[(size_t)n * HCdim + h * CC + lane] = acc / (s + 1e-16f);
}

// K5: out = aggrN @ Ws + bias, 16 staged rows, 4-row register blocking per wave.
#define K5_ROWS 16
__global__ __launch_bounds__(256) void tm_k5(const float* __restrict__ aggrN,
        const float* __restrict__ Ws, const float* __restrict__ bias,
        float* __restrict__ out, int N) {
    __shared__ float wsl[HCdim * CC];      // 48 KiB [k][c]
    __shared__ float al[K5_ROWS * HCdim];  // 12 KiB [r][k]
    const int t = threadIdx.x;
    const int part = t >> 6, c = t & 63;
    {
        float4* w4 = (float4*)wsl;
        const float4* Ws4 = (const float4*)Ws;
        for (int i = t; i < HCdim * CC / 4; i += 256) w4[i] = Ws4[i];
    }
    const float b = bias[c];
    const int base = blockIdx.x * K5_ROWS;
    const int rows = min(K5_ROWS, N - base);
    {
        float4* al4 = (float4*)al;
        const float4* a4 = (const float4*)(aggrN + (size_t)base * HCdim);
        for (int i = t; i < rows * HCdim / 4; i += 256) al4[i] = a4[i];
    }
    __syncthreads();
    const int r0 = part * 4;
    if (r0 >= rows) return;
    float acc0 = b, acc1 = b, acc2 = b, acc3 = b;
    #pragma unroll 4
    for (int k = 0; k < HCdim; k += 4) {
        const float w0  = wsl[(k + 0) * CC + c];
        const float w1  = wsl[(k + 1) * CC + c];
        const float w2_ = wsl[(k + 2) * CC + c];
        const float w3  = wsl[(k + 3) * CC + c];
        const float4 xa = *(const float4*)&al[(r0 + 0) * HCdim + k];
        const float4 xb = *(const float4*)&al[(r0 + 1) * HCdim + k];
        const float4 xc = *(const float4*)&al[(r0 + 2) * HCdim + k];
        const float4 xd = *(const float4*)&al[(r0 + 3) * HCdim + k];
        acc0 = fmaf(xa.x, w0, fmaf(xa.y, w1, fmaf(xa.z, w2_, fmaf(xa.w, w3, acc0))));
        acc1 = fmaf(xb.x, w0, fmaf(xb.y, w1, fmaf(xb.z, w2_, fmaf(xb.w, w3, acc1))));
        acc2 = fmaf(xc.x, w0, fmaf(xc.y, w1, fmaf(xc.z, w2_, fmaf(xc.w, w3, acc2))));
        acc3 = fmaf(xd.x, w0, fmaf(xd.y, w1, fmaf(xd.z, w2_, fmaf(xd.w, w3, acc3))));
    }
    if (r0 + 0 < rows) out[(size_t)(base + r0 + 0) * CC + c] = acc0;
    if (r0 + 1 < rows) out[(size_t)(base + r0 + 1) * CC + c] = acc1;
    if (r0 + 2 < rows) out[(size_t)(base + r0 + 2) * CC + c] = acc2;
    if (r0 + 3 < rows) out[(size_t)(base + r0 + 3) * CC + c] = acc3;
}

extern "C" void kernel_launch(void* const* d_in, const int* in_sizes, int n_in,
                              void* d_out, int out_size, void* d_ws, size_t ws_size,
                              hipStream_t stream) {
    const float* x    = (const float*)d_in[0];
    const int*   ei   = (const int*)d_in[1];
    const float* ea   = (const float*)d_in[2];
    const float* Wn   = (const float*)d_in[3];
    const float* We   = (const float*)d_in[4];
    const float* wt   = (const float*)d_in[5];
    const float* Ws   = (const float*)d_in[6];
    const float* bias = (const float*)d_in[7];
    float* out = (float*)d_out;
    const int N = in_sizes[0] / CC;
    const int E = in_sizes[1] / 2;
    const int nb = (N + 255) / 256;          // scan blocks (<= 256)

    // workspace layout (floats; 16B alignment kept for float4/int2 buffers)
    float* ws = (float*)d_ws;
    size_t o = 0;
    float* xp = ws + o;                  o += (size_t)N * HCdim;   // 38.4 MB
    float* sA = ws + o;                  o += (size_t)N * 8;       // 1.6 MB
    float* u  = ws + o;                  o += 128;
    float4* alphaP = (float4*)(ws + o);  o += (size_t)E * 4;       // 12.8 MB
    int2*  perm = (int2*)(ws + o);       o += (size_t)E * 2;       // 6.4 MB
    int* deg    = (int*)(ws + o);        o += N;
    unsigned* segmax = (unsigned*)(ws + o); o += (size_t)N * HH;
    int* off    = (int*)(ws + o);        o += N + 1;
    int* cursor = (int*)(ws + o);        o += N;
    int* bsum   = (int*)(ws + o);        o += 256;
    int* boff   = (int*)(ws + o);        o += 256;
    o += (4 - (o & 3)) & 3;              // realign
    float* aggrN = ws + o;               o += (size_t)N * HCdim;   // 38.4 MB
    (void)ws_size; (void)n_in; (void)out_size;

    // zero deg + segmax (adjacent)
    (void)hipMemsetAsync(deg, 0, (size_t)N * (1 + HH) * sizeof(int), stream);

    tm_k0<<<1, 96, 0, stream>>>(We, wt, u);
    tm_k1<<<(N + K1_ROWS - 1) / K1_ROWS, 192, 0, stream>>>(x, Wn, wt, xp, sA, N);
    tm_deg<<<(E + 255) / 256, 256, 0, stream>>>(ei, deg, E);
    tm_scanA<<<nb, 256, 0, stream>>>(deg, bsum, N);
    tm_scanB<<<1, 256, 0, stream>>>(bsum, boff, nb);
    tm_scanC<<<nb, 256, 0, stream>>>(deg, boff, off, cursor, N);
    tm_scatter2<<<(E + 255) / 256, 256, 0, stream>>>(ei, ea, u, sA, cursor,
                                                     perm, alphaP, segmax, E);
    tm_agg<<<N, 192, 0, stream>>>(perm, off, ea, We, (const float*)alphaP,
                                  segmax, xp, aggrN, N);
    tm_k5<<<(N + K5_ROWS - 1) / K5_ROWS, 256, 0, stream>>>(aggrN, Ws, bias, out, N);
}

// Round 8
// 529.175 us; speedup vs baseline: 1.0248x; 1.0248x over previous
//
#include <hip/hip_runtime.h>

#define CC    64
#define HH    3
#define ECC   32
#define HCdim 192
#define NEG_SLOPE 0.2f

typedef float v2f __attribute__((ext_vector_type(2)));

// ---- float <-> monotone uint key (for atomicMax on floats) ----
__device__ __forceinline__ unsigned fkey(float f) {
    int i = __float_as_int(f);
    return (i < 0) ? ~((unsigned)i) : (((unsigned)i) | 0x80000000u);
}
__device__ __forceinline__ float funkey(unsigned k) {
    int i = (k & 0x80000000u) ? (int)(k ^ 0x80000000u) : ~((int)k);
    return __int_as_float(i);
}

// K0: u[h*32+k] = sum_c We[k*192 + h*64 + c] * wt[h*192 + 64 + c]
__global__ void tm_k0(const float* __restrict__ We, const float* __restrict__ wt,
                      float* __restrict__ u) {
    int t = threadIdx.x;
    if (t >= HH * ECC) return;
    int h = t >> 5, k = t & 31;
    float s = 0.f;
    #pragma unroll
    for (int c = 0; c < CC; ++c)
        s = fmaf(We[k * HCdim + h * CC + c], wt[h * HCdim + CC + c], s);
    u[t] = s;
}

// K1: xp = x @ Wn (N x 64 @ 64 x 192), 4-row register blocking,
// fused per-node scalars sA. (NOT 8-row: that blew VGPR to 256 in R5.)
#define K1_ROWS 64
__global__ __launch_bounds__(192) void tm_k1(const float* __restrict__ x,
        const float* __restrict__ Wn, const float* __restrict__ wt,
        float* __restrict__ xp, float* __restrict__ sA, int N) {
    __shared__ float wl[CC * HCdim];     // 48 KiB [k][t]
    __shared__ float xl[K1_ROWS * CC];   // 16 KiB [r][k]
    const int t = threadIdx.x;
    const int h = t >> 6, c = t & 63;
    {
        float4* wl4 = (float4*)wl;
        const float4* Wn4 = (const float4*)Wn;
        for (int i = t; i < CC * HCdim / 4; i += 192) wl4[i] = Wn4[i];
    }
    const int base = blockIdx.x * K1_ROWS;
    const int rows = min(K1_ROWS, N - base);   // N%4==0 so rows%4==0
    {
        float4* xl4 = (float4*)xl;
        const float4* x4 = (const float4*)(x + (size_t)base * CC);
        for (int i = t; i < rows * CC / 4; i += 192) xl4[i] = x4[i];
    }
    const float w0c = wt[h * HCdim + c];
    const float w2c = wt[h * HCdim + 2 * CC + c];
    __syncthreads();
    for (int rt = 0; rt < rows; rt += 4) {
        float acc0 = 0.f, acc1 = 0.f, acc2 = 0.f, acc3 = 0.f;
        #pragma unroll 4
        for (int k = 0; k < CC; k += 4) {
            const float w0  = wl[(k + 0) * HCdim + t];
            const float w1  = wl[(k + 1) * HCdim + t];
            const float w2_ = wl[(k + 2) * HCdim + t];
            const float w3  = wl[(k + 3) * HCdim + t];
            const float4 xa = *(const float4*)&xl[(rt + 0) * CC + k];
            const float4 xb = *(const float4*)&xl[(rt + 1) * CC + k];
            const float4 xc = *(const float4*)&xl[(rt + 2) * CC + k];
            const float4 xd = *(const float4*)&xl[(rt + 3) * CC + k];
            acc0 = fmaf(xa.x, w0, fmaf(xa.y, w1, fmaf(xa.z, w2_, fmaf(xa.w, w3, acc0))));
            acc1 = fmaf(xb.x, w0, fmaf(xb.y, w1, fmaf(xb.z, w2_, fmaf(xb.w, w3, acc1))));
            acc2 = fmaf(xc.x, w0, fmaf(xc.y, w1, fmaf(xc.z, w2_, fmaf(xc.w, w3, acc2))));
            acc3 = fmaf(xd.x, w0, fmaf(xd.y, w1, fmaf(xd.z, w2_, fmaf(xd.w, w3, acc3))));
        }
        #pragma unroll
        for (int r = 0; r < 4; ++r) {
            const float v = (r == 0) ? acc0 : (r == 1) ? acc1 : (r == 2) ? acc2 : acc3;
            const int n = base + rt + r;
            xp[(size_t)n * HCdim + t] = v;
            float a0 = v * w0c, a2 = v * w2c;
            #pragma unroll
            for (int o = 32; o; o >>= 1) {
                a0 += __shfl_xor(a0, o);
                a2 += __shfl_xor(a2, o);
            }
            if (c == 0) {
                sA[n * 8 + h]     = a0;
                sA[n * 8 + 4 + h] = a2;
            }
        }
    }
}

// K_alpha (edge-order, all writes coalesced except atomics):
//   alphaE[e] = {a0,a1,a2,0}; segmax atomicMax; deg histogram (fused).
__global__ __launch_bounds__(256) void tm_alpha(const int* __restrict__ ei,
        const float* __restrict__ ea, const float* __restrict__ u,
        const float* __restrict__ sA, float4* __restrict__ alphaE,
        unsigned* __restrict__ segmax, int* __restrict__ deg, int E) {
    __shared__ float ul[HH * ECC];
    const int t = threadIdx.x;
    if (t < HH * ECC) ul[t] = u[t];
    __syncthreads();
    const int e = blockIdx.x * 256 + t;
    if (e >= E) return;
    const int src = ei[e];
    const int dst = ei[E + e];
    atomicAdd(&deg[dst], 1);
    float av[ECC];
    const float4* p4 = (const float4*)(ea + (size_t)e * ECC);
    #pragma unroll
    for (int q = 0; q < 8; ++q) {
        float4 v = p4[q];
        av[4*q] = v.x; av[4*q+1] = v.y; av[4*q+2] = v.z; av[4*q+3] = v.w;
    }
    float d0 = 0.f, d1 = 0.f, d2 = 0.f;
    #pragma unroll
    for (int k = 0; k < ECC; ++k) {
        d0 = fmaf(av[k], ul[k], d0);
        d1 = fmaf(av[k], ul[ECC + k], d1);
        d2 = fmaf(av[k], ul[2 * ECC + k], d2);
    }
    const float4 s0 = *(const float4*)(sA + (size_t)dst * 8);
    const float4 s2 = *(const float4*)(sA + (size_t)src * 8 + 4);
    float a0 = s0.x + d0 + s2.x;
    float a1 = s0.y + d1 + s2.y;
    float a2 = s0.z + d2 + s2.z;
    a0 = (a0 >= 0.f) ? a0 : NEG_SLOPE * a0;
    a1 = (a1 >= 0.f) ? a1 : NEG_SLOPE * a1;
    a2 = (a2 >= 0.f) ? a2 : NEG_SLOPE * a2;
    alphaE[e] = make_float4(a0, a1, a2, 0.f);
    atomicMax(&segmax[dst * 3 + 0], fkey(a0));
    atomicMax(&segmax[dst * 3 + 1], fkey(a1));
    atomicMax(&segmax[dst * 3 + 2], fkey(a2));
}

// scanA: per-block (256) sums of deg
__global__ __launch_bounds__(256) void tm_scanA(const int* __restrict__ deg,
        int* __restrict__ bsum, int N) {
    __shared__ int sd[256];
    int t = threadIdx.x, n = blockIdx.x * 256 + t;
    sd[t] = (n < N) ? deg[n] : 0;
    __syncthreads();
    for (int o = 128; o; o >>= 1) {
        if (t < o) sd[t] += sd[t + o];
        __syncthreads();
    }
    if (!t) bsum[blockIdx.x] = sd[0];
}

// scanB: exclusive scan of block sums (nb <= 256), single block
__global__ __launch_bounds__(256) void tm_scanB(const int* __restrict__ bsum,
        int* __restrict__ boff, int nb) {
    __shared__ int sd[256];
    int t = threadIdx.x;
    int v = (t < nb) ? bsum[t] : 0;
    sd[t] = v;
    __syncthreads();
    for (int o = 1; o < 256; o <<= 1) {
        int x = (t >= o) ? sd[t - o] : 0;
        __syncthreads();
        sd[t] += x;
        __syncthreads();
    }
    if (t < nb) boff[t] = sd[t] - v;   // exclusive
}

// scanC: per-element exclusive offsets; off[N]=E; cursor=off copy
__global__ __launch_bounds__(256) void tm_scanC(const int* __restrict__ deg,
        const int* __restrict__ boff, int* __restrict__ off,
        int* __restrict__ cursor, int N) {
    __shared__ int sd[256];
    int t = threadIdx.x, n = blockIdx.x * 256 + t;
    int v = (n < N) ? deg[n] : 0;
    sd[t] = v;
    __syncthreads();
    for (int o = 1; o < 256; o <<= 1) {
        int x = (t >= o) ? sd[t - o] : 0;
        __syncthreads();
        sd[t] += x;
        __syncthreads();
    }
    if (n < N) {
        int ex = boff[blockIdx.x] + sd[t] - v;
        off[n] = ex;
        cursor[n] = ex;
        if (n == N - 1) off[N] = ex + v;
    }
}

// K_scatter (slim): only the 8B perm entry is scattered.
__global__ __launch_bounds__(256) void tm_scatter(const int* __restrict__ ei,
        int* __restrict__ cursor, int2* __restrict__ perm, int E) {
    const int e = blockIdx.x * 256 + threadIdx.x;
    if (e >= E) return;
    const int src = ei[e];
    const int dst = ei[E + e];
    const int pos = atomicAdd(&cursor[dst], 1);
    perm[pos] = make_int2(src * (HCdim * 4), e * (ECC * 4));
}

// K_agg: one block (3 waves = 3 heads) per dst node. Branch-free, pk_fma dot,
// byte-offset addressing, 2x unroll (4x regressed in R7). alpha read through
// the edge-id indirection: alphaE byte offset = eo>>3 (+h*4).
__global__ __launch_bounds__(192) void tm_agg(const int2* __restrict__ perm,
        const int* __restrict__ off, const float* __restrict__ ea,
        const float* __restrict__ We, const float* __restrict__ alphaE,
        const unsigned* __restrict__ segmax, const float* __restrict__ xp,
        float* __restrict__ aggrN, int N) {
    const int n = blockIdx.x;
    const int t = threadIdx.x;
    const int h = t >> 6, lane = t & 63;
    const char* __restrict__ ea_b = (const char*)ea;
    const char* __restrict__ xp_b = (const char*)xp;
    const char* __restrict__ al_b = (const char*)alphaE;
    v2f wcol2[16];
    #pragma unroll
    for (int k2 = 0; k2 < 16; ++k2) {
        wcol2[k2].x = We[(2 * k2)     * HCdim + h * CC + lane];
        wcol2[k2].y = We[(2 * k2 + 1) * HCdim + h * CC + lane];
    }
    const float m = funkey(segmax[n * 3 + h]);
    const int xoff = h * CC * 4 + lane * 4;  // byte offset within an xp row
    const int aoff = h * 4;                  // byte offset within alphaE entry
    const int start = off[n], end = off[n + 1];
    float s = 0.f, acc = 0.f;
    int pos = start;
    for (; pos + 2 <= end; pos += 2) {
        const int4 pp = *(const int4*)&perm[pos];   // {so0,eo0,so1,eo1}
        const int so0 = __builtin_amdgcn_readfirstlane(pp.x);
        const int eo0 = __builtin_amdgcn_readfirstlane(pp.y);
        const int so1 = __builtin_amdgcn_readfirstlane(pp.z);
        const int eo1 = __builtin_amdgcn_readfirstlane(pp.w);
        const float a0 = *(const float*)(al_b + (eo0 >> 3) + aoff);
        const float a1 = *(const float*)(al_b + (eo1 >> 3) + aoff);
        const float4* q0 = (const float4*)(ea_b + eo0);
        const float4* q1 = (const float4*)(ea_b + eo1);
        const float xj0 = *(const float*)(xp_b + so0 + xoff);
        const float xj1 = *(const float*)(xp_b + so1 + xoff);
        v2f d0 = {0.f, 0.f}, d1 = {0.f, 0.f};
        #pragma unroll
        for (int q = 0; q < 8; ++q) {
            const float4 v0 = q0[q];
            const float4 v1 = q1[q];
            const v2f wlo = wcol2[2 * q], whi = wcol2[2 * q + 1];
            d0 = (v2f){v0.x, v0.y} * wlo + d0;
            d0 = (v2f){v0.z, v0.w} * whi + d0;
            d1 = (v2f){v1.x, v1.y} * wlo + d1;
            d1 = (v2f){v1.z, v1.w} * whi + d1;
        }
        const float p0 = __expf(a0 - m);
        const float p1 = __expf(a1 - m);
        s += p0 + p1;
        acc = fmaf(p0 * (d0.x + d0.y), xj0, acc);
        acc = fmaf(p1 * (d1.x + d1.y), xj1, acc);
    }
    if (pos < end) {
        const int2 pe = perm[pos];
        const int so = __builtin_amdgcn_readfirstlane(pe.x);
        const int eo = __builtin_amdgcn_readfirstlane(pe.y);
        const float a = *(const float*)(al_b + (eo >> 3) + aoff);
        const float4* q4 = (const float4*)(ea_b + eo);
        const float xj = *(const float*)(xp_b + so + xoff);
        v2f d = {0.f, 0.f};
        #pragma unroll
        for (int q = 0; q < 8; ++q) {
            const float4 v = q4[q];
            d = (v2f){v.x, v.y} * wcol2[2 * q]     + d;
            d = (v2f){v.z, v.w} * wcol2[2 * q + 1] + d;
        }
        const float p = __expf(a - m);
        s += p;
        acc = fmaf(p * (d.x + d.y), xj, acc);
    }
    aggrN[(size_t)n * HCdim + h * CC + lane] = acc / (s + 1e-16f);
}

// K5: out = aggrN @ Ws + bias, 16 staged rows, 4-row register blocking per wave.
#define K5_ROWS 16
__global__ __launch_bounds__(256) void tm_k5(const float* __restrict__ aggrN,
        const float* __restrict__ Ws, const float* __restrict__ bias,
        float* __restrict__ out, int N) {
    __shared__ float wsl[HCdim * CC];      // 48 KiB [k][c]
    __shared__ float al[K5_ROWS * HCdim];  // 12 KiB [r][k]
    const int t = threadIdx.x;
    const int part = t >> 6, c = t & 63;
    {
        float4* w4 = (float4*)wsl;
        const float4* Ws4 = (const float4*)Ws;
        for (int i = t; i < HCdim * CC / 4; i += 256) w4[i] = Ws4[i];
    }
    const float b = bias[c];
    const int base = blockIdx.x * K5_ROWS;
    const int rows = min(K5_ROWS, N - base);
    {
        float4* al4 = (float4*)al;
        const float4* a4 = (const float4*)(aggrN + (size_t)base * HCdim);
        for (int i = t; i < rows * HCdim / 4; i += 256) al4[i] = a4[i];
    }
    __syncthreads();
    const int r0 = part * 4;
    if (r0 >= rows) return;
    float acc0 = b, acc1 = b, acc2 = b, acc3 = b;
    #pragma unroll 4
    for (int k = 0; k < HCdim; k += 4) {
        const float w0  = wsl[(k + 0) * CC + c];
        const float w1  = wsl[(k + 1) * CC + c];
        const float w2_ = wsl[(k + 2) * CC + c];
        const float w3  = wsl[(k + 3) * CC + c];
        const float4 xa = *(const float4*)&al[(r0 + 0) * HCdim + k];
        const float4 xb = *(const float4*)&al[(r0 + 1) * HCdim + k];
        const float4 xc = *(const float4*)&al[(r0 + 2) * HCdim + k];
        const float4 xd = *(const float4*)&al[(r0 + 3) * HCdim + k];
        acc0 = fmaf(xa.x, w0, fmaf(xa.y, w1, fmaf(xa.z, w2_, fmaf(xa.w, w3, acc0))));
        acc1 = fmaf(xb.x, w0, fmaf(xb.y, w1, fmaf(xb.z, w2_, fmaf(xb.w, w3, acc1))));
        acc2 = fmaf(xc.x, w0, fmaf(xc.y, w1, fmaf(xc.z, w2_, fmaf(xc.w, w3, acc2))));
        acc3 = fmaf(xd.x, w0, fmaf(xd.y, w1, fmaf(xd.z, w2_, fmaf(xd.w, w3, acc3))));
    }
    if (r0 + 0 < rows) out[(size_t)(base + r0 + 0) * CC + c] = acc0;
    if (r0 + 1 < rows) out[(size_t)(base + r0 + 1) * CC + c] = acc1;
    if (r0 + 2 < rows) out[(size_t)(base + r0 + 2) * CC + c] = acc2;
    if (r0 + 3 < rows) out[(size_t)(base + r0 + 3) * CC + c] = acc3;
}

extern "C" void kernel_launch(void* const* d_in, const int* in_sizes, int n_in,
                              void* d_out, int out_size, void* d_ws, size_t ws_size,
                              hipStream_t stream) {
    const float* x    = (const float*)d_in[0];
    const int*   ei   = (const int*)d_in[1];
    const float* ea   = (const float*)d_in[2];
    const float* Wn   = (const float*)d_in[3];
    const float* We   = (const float*)d_in[4];
    const float* wt   = (const float*)d_in[5];
    const float* Ws   = (const float*)d_in[6];
    const float* bias = (const float*)d_in[7];
    float* out = (float*)d_out;
    const int N = in_sizes[0] / CC;
    const int E = in_sizes[1] / 2;
    const int nb = (N + 255) / 256;          // scan blocks (<= 256)

    // workspace layout (floats; 16B alignment kept for float4/int2 buffers)
    float* ws = (float*)d_ws;
    size_t o = 0;
    float* xp = ws + o;                  o += (size_t)N * HCdim;   // 38.4 MB
    float* sA = ws + o;                  o += (size_t)N * 8;       // 1.6 MB
    float* u  = ws + o;                  o += 128;
    float4* alphaE = (float4*)(ws + o);  o += (size_t)E * 4;       // 12.8 MB
    int2*  perm = (int2*)(ws + o);       o += (size_t)E * 2;       // 6.4 MB
    int* deg    = (int*)(ws + o);        o += N;
    unsigned* segmax = (unsigned*)(ws + o); o += (size_t)N * HH;
    int* off    = (int*)(ws + o);        o += N + 1;
    int* cursor = (int*)(ws + o);        o += N;
    int* bsum   = (int*)(ws + o);        o += 256;
    int* boff   = (int*)(ws + o);        o += 256;
    o += (4 - (o & 3)) & 3;              // realign
    float* aggrN = ws + o;               o += (size_t)N * HCdim;   // 38.4 MB
    (void)ws_size; (void)n_in; (void)out_size;

    // zero deg + segmax (adjacent)
    (void)hipMemsetAsync(deg, 0, (size_t)N * (1 + HH) * sizeof(int), stream);

    tm_k0<<<1, 96, 0, stream>>>(We, wt, u);
    tm_k1<<<(N + K1_ROWS - 1) / K1_ROWS, 192, 0, stream>>>(x, Wn, wt, xp, sA, N);
    tm_alpha<<<(E + 255) / 256, 256, 0, stream>>>(ei, ea, u, sA, alphaE,
                                                  segmax, deg, E);
    tm_scanA<<<nb, 256, 0, stream>>>(deg, bsum, N);
    tm_scanB<<<1, 256, 0, stream>>>(bsum, boff, nb);
    tm_scanC<<<nb, 256, 0, stream>>>(deg, boff, off, cursor, N);
    tm_scatter<<<(E + 255) / 256, 256, 0, stream>>>(ei, cursor, perm, E);
    tm_agg<<<N, 192, 0, stream>>>(perm, off, ea, We, (const float*)alphaE,
                                  segmax, xp, aggrN, N);
    tm_k5<<<(N + K5_ROWS - 1) / K5_ROWS, 256, 0, stream>>>(aggrN, Ws, bias, out, N);
}